// Round 3
// baseline (7558.701 us; speedup 1.0000x reference)
//
#include <hip/hip_runtime.h>

#define RD     128
#define TT     128
#define TLEN   16384
#define NB     8
#define NLAYER 63
#define N0SKIP 27
#define NSKIP  36
#define QD     256
#define PADR   136   // padded LDS row stride (shorts): 4n-bank pattern, 2-way = free
#define CROWS  192   // circular staging window rows (52.2 KB -> 3 blocks/CU)

typedef short bf16x8 __attribute__((ext_vector_type(8)));
typedef float f32x4  __attribute__((ext_vector_type(4)));

__device__ __forceinline__ unsigned short f2bf(float f) {
  unsigned u = __float_as_uint(f);
  u += 0x7fffu + ((u >> 16) & 1u);
  return (unsigned short)(u >> 16);
}
__device__ __forceinline__ short f2bf_relu(float f) {
  f = f > 0.f ? f : 0.f;
  unsigned u = __float_as_uint(f);
  u += 0x7fffu + ((u >> 16) & 1u);
  return (short)(u >> 16);
}

__device__ __forceinline__ void zero_acc(f32x4 (&acc)[4][4]) {
#pragma unroll
  for (int i = 0; i < 4; ++i)
#pragma unroll
    for (int j = 0; j < 4; ++j) acc[i][j] = (f32x4){0.f, 0.f, 0.f, 0.f};
}

__device__ __forceinline__ void mk_rows(int rows[4], int t0w, int n, int s) {
#pragma unroll
  for (int tt = 0; tt < 4; ++tt) {
    int r = t0w + tt * 16 + n + s;
    if (r >= CROWS) r -= CROWS;
    rows[tt] = r;
  }
}

// acc[ct][tt] += W[c][i] * H[i][t] ; W bf16 global [128c][128i], H LDS [row][i]
__device__ __forceinline__ void mfma_gemm(const unsigned short* __restrict__ aw,
                                          const short* sx, const int rows[4],
                                          int c0w, int n, int q,
                                          f32x4 (&acc)[4][4]) {
#pragma unroll
  for (int ks = 0; ks < 4; ++ks) {
    const int i0 = ks * 32 + q * 8;
    bf16x8 a[4], bb[4];
#pragma unroll
    for (int ct = 0; ct < 4; ++ct)
      a[ct] = *(const bf16x8*)&aw[(size_t)(c0w + ct * 16 + n) * RD + i0];
#pragma unroll
    for (int tt = 0; tt < 4; ++tt)
      bb[tt] = *(const bf16x8*)&sx[rows[tt] * PADR + i0];
#pragma unroll
    for (int ct = 0; ct < 4; ++ct)
#pragma unroll
      for (int tt = 0; tt < 4; ++tt)
        acc[ct][tt] = __builtin_amdgcn_mfma_f32_16x16x32_bf16(a[ct], bb[tt],
                                                              acc[ct][tt], 0, 0, 0);
  }
}

// stage bf16 rows from global [t][c] into circular LDS window
__device__ __forceinline__ void stage_circ(short* sx, const unsigned short* __restrict__ xrb,
                                           int tstart, int count, int slot0, int tid) {
  const int tot = count << 4;
  for (int idx = tid; idx < tot; idx += 256) {
    const int r = idx >> 4, ck = (idx & 15) << 3;
    const int tg = tstart + r;
    int4 v = {0, 0, 0, 0};
    if ((unsigned)tg < (unsigned)TLEN)
      v = *(const int4*)&xrb[(size_t)tg * RD + ck];
    int slot = slot0 + r;
    if (slot >= CROWS) slot -= CROWS;
    *(int4*)&sx[slot * PADR + ck] = v;
  }
}

// stage full 128-row bf16 tile (no bounds) into LDS
__device__ __forceinline__ void stage_tile(short* dst, const unsigned short* __restrict__ src,
                                           int tid) {
  for (int idx = tid; idx < 128 * 16; idx += 256) {
    const int r = idx >> 4, ck = (idx & 15) << 3;
    *(int4*)&dst[r * PADR + ck] = *(const int4*)&src[(size_t)r * RD + ck];
  }
}

// relu(acc + bias) -> LDS bf16 [t][c]
__device__ __forceinline__ void store_act_bf16(short* dst, const f32x4 (&acc)[4][4],
                                               const float* __restrict__ bias,
                                               int c0w, int t0w, int n, int q) {
#pragma unroll
  for (int ct = 0; ct < 4; ++ct) {
    const int c = c0w + ct * 16 + q * 4;
    const float4 bb = *(const float4*)&bias[c];
#pragma unroll
    for (int tt = 0; tt < 4; ++tt) {
      const int t = t0w + tt * 16 + n;
      const f32x4 A = acc[ct][tt];
      short4 o;
      o.x = f2bf_relu(A[0] + bb.x);
      o.y = f2bf_relu(A[1] + bb.y);
      o.z = f2bf_relu(A[2] + bb.z);
      o.w = f2bf_relu(A[3] + bb.w);
      *(short4*)&dst[t * PADR + c] = o;
    }
  }
}

// dst[t][c] = src[t][c] + acc + bias  (fp32 [T][C] tiles)
__device__ __forceinline__ void epi_accum(float* __restrict__ dst,
                                          const float* __restrict__ src,
                                          const float* __restrict__ bias,
                                          const f32x4 (&acc)[4][4],
                                          int c0w, int t0w, int n, int q) {
#pragma unroll
  for (int ct = 0; ct < 4; ++ct) {
    const int c = c0w + ct * 16 + q * 4;
    const float4 bb = *(const float4*)&bias[c];
#pragma unroll
    for (int tt = 0; tt < 4; ++tt) {
      const int t = t0w + tt * 16 + n;
      float4 r = *(const float4*)&src[(size_t)t * RD + c];
      const f32x4 A = acc[ct][tt];
      r.x += A[0] + bb.x; r.y += A[1] + bb.y;
      r.z += A[2] + bb.z; r.w += A[3] + bb.w;
      *(float4*)&dst[(size_t)t * RD + c] = r;
    }
  }
}

// ---------------------------------------------------------------------------
// Fused WaveNet layer. xr_in = relu(x_in) bf16 [B][T][C]; x fp32 [B][T][C].
// ---------------------------------------------------------------------------
__global__ __launch_bounds__(256, 3) void layer_kernel(
    const unsigned short* __restrict__ xr_in, const float* __restrict__ x_in,
    float* __restrict__ x_out, unsigned short* __restrict__ xr_out,
    unsigned short* __restrict__ h_out,   // bf16 h tile out (deferred skip) or null
    float* __restrict__ skip,             // fp32 skip RMW (fallback) or null
    const unsigned short* __restrict__ wconv, const float* __restrict__ bconv,
    const unsigned short* __restrict__ wdense, const float* __restrict__ bdense,
    const unsigned short* __restrict__ wskip, const float* __restrict__ bskip,
    int dil) {
  __shared__ short sx[CROWS * PADR];   // 52,224 B

  const int tid = threadIdx.x;
  const int b   = blockIdx.x >> 7;
  const int t0  = (blockIdx.x & 127) << 7;
  const int lane = tid & 63;
  const int n = lane & 15, q = lane >> 4;
  const int w = tid >> 6;
  const int c0w = (w & 1) * 64, t0w = (w >> 1) * 64;
  const unsigned short* xrb = xr_in + (size_t)b * TLEN * RD;

  f32x4 acc[4][4];
  zero_acc(acc);
  int rows[4];

  if (dil <= 32) {
    stage_circ(sx, xrb, t0 - dil, 128 + 2 * dil, 0, tid);
    __syncthreads();
#pragma unroll
    for (int k = 0; k < 3; ++k) {
      mk_rows(rows, t0w, n, k * dil);
      mfma_gemm(wconv + (size_t)k * RD * RD, sx, rows, c0w, n, q, acc);
    }
  } else if (dil == 64) {
    stage_circ(sx, xrb, t0 - 64, 192, 0, tid);
    __syncthreads();
    mk_rows(rows, t0w, n, 0);
    mfma_gemm(wconv, sx, rows, c0w, n, q, acc);
    mk_rows(rows, t0w, n, 64);
    mfma_gemm(wconv + (size_t)RD * RD, sx, rows, c0w, n, q, acc);
    __syncthreads();
    stage_circ(sx, xrb, t0 + 128, 64, 0, tid);
    __syncthreads();
    mk_rows(rows, t0w, n, 128);
    mfma_gemm(wconv + (size_t)2 * RD * RD, sx, rows, c0w, n, q, acc);
  } else {          // dil in {128, 256}
    for (int k = 0; k < 3; ++k) {
      const int s = (k * dil) % CROWS;
      stage_circ(sx, xrb, t0 + (k - 1) * dil, 128, s, tid);
      __syncthreads();
      mk_rows(rows, t0w, n, s);
      mfma_gemm(wconv + (size_t)k * RD * RD, sx, rows, c0w, n, q, acc);
      __syncthreads();
    }
  }
  __syncthreads();

  // h = relu(conv + bconv) -> LDS rows [0,128)
  store_act_bf16(sx, acc, bconv, c0w, t0w, n, q);
  __syncthreads();

  // deferred skip: stream h tile to global (coalesced from LDS)
  if (h_out) {
    unsigned short* hb = h_out + ((size_t)b * TLEN + t0) * RD;
    for (int idx = tid; idx < 128 * 16; idx += 256) {
      const int r = idx >> 4, ck = (idx & 15) << 3;
      *(int4*)&hb[(size_t)r * RD + ck] = *(const int4*)&sx[r * PADR + ck];
    }
  }

  // dense GEMM + residual + relu-bf16 chain write
  zero_acc(acc);
  mk_rows(rows, t0w, n, 0);
  mfma_gemm(wdense, sx, rows, c0w, n, q, acc);
  {
    const size_t rowb = (size_t)b * TLEN + t0;
    float* xo = x_out + rowb * RD;
    const float* xi = x_in + rowb * RD;
    unsigned short* xro = xr_out + rowb * RD;
#pragma unroll
    for (int ct = 0; ct < 4; ++ct) {
      const int c = c0w + ct * 16 + q * 4;
      const float4 bb = *(const float4*)&bdense[c];
#pragma unroll
      for (int tt = 0; tt < 4; ++tt) {
        const int t = t0w + tt * 16 + n;
        float4 r = *(const float4*)&xi[(size_t)t * RD + c];
        const f32x4 A = acc[ct][tt];
        r.x += A[0] + bb.x; r.y += A[1] + bb.y;
        r.z += A[2] + bb.z; r.w += A[3] + bb.w;
        *(float4*)&xo[(size_t)t * RD + c] = r;
        short4 o;
        o.x = f2bf_relu(r.x); o.y = f2bf_relu(r.y);
        o.z = f2bf_relu(r.z); o.w = f2bf_relu(r.w);
        *(short4*)&xro[(size_t)t * RD + c] = o;
      }
    }
  }

  // fallback: per-layer skip GEMM + RMW
  if (skip) {
    zero_acc(acc);
    mfma_gemm(wskip, sx, rows, c0w, n, q, acc);
    float* sp = skip + ((size_t)b * TLEN + t0) * RD;
    epi_accum(sp, sp, bskip, acc, c0w, t0w, n, q);
  }
}

// ---------------------------------------------------------------------------
// Gather: skip-sum over nl h-buffers (double-buffered), optional skip fp32 io,
// optional fused post network + output write.
// ---------------------------------------------------------------------------
__global__ __launch_bounds__(256, 2) void gather_kernel(
    const unsigned short* __restrict__ h, int nl,
    const unsigned short* __restrict__ wsk_g,
    float* __restrict__ skip_io, int skip_rd, int skip_wr, int do_final,
    const float* __restrict__ bsum,
    const unsigned short* __restrict__ p1, const float* __restrict__ p1b,
    const unsigned short* __restrict__ p2, const float* __restrict__ p2b,
    float* __restrict__ out) {
  __shared__ short buf[2][128 * PADR];   // 69,632 B

  const int tid = threadIdx.x;
  const int b   = blockIdx.x >> 7;
  const int t0  = (blockIdx.x & 127) << 7;
  const int lane = tid & 63;
  const int n = lane & 15, q = lane >> 4;
  const int w = tid >> 6;
  const int c0w = (w & 1) * 64, t0w = (w >> 1) * 64;
  const size_t tilebase = ((size_t)b * TLEN + t0) * RD;
  const size_t XNE = (size_t)NB * TLEN * RD;

  f32x4 acc[4][4];
  zero_acc(acc);
  int rows[4];
  mk_rows(rows, t0w, n, 0);

  if (nl > 0) {
    stage_tile(buf[0], h + tilebase, tid);
    __syncthreads();
    for (int li = 0; li < nl; ++li) {
      const int cur = li & 1;
      if (li + 1 < nl)
        stage_tile(buf[cur ^ 1], h + (size_t)(li + 1) * XNE + tilebase, tid);
      mfma_gemm(wsk_g + (size_t)li * RD * RD, buf[cur], rows, c0w, n, q, acc);
      __syncthreads();
    }
  }

  if (!do_final) {
    // write or accumulate fp32 skip
    float* sp = skip_io + tilebase;
#pragma unroll
    for (int ct = 0; ct < 4; ++ct) {
      const int c = c0w + ct * 16 + q * 4;
#pragma unroll
      for (int tt = 0; tt < 4; ++tt) {
        const int t = t0w + tt * 16 + n;
        const f32x4 A = acc[ct][tt];
        float4 r = make_float4(A[0], A[1], A[2], A[3]);
        if (skip_rd) {
          const float4 s = *(const float4*)&sp[(size_t)t * RD + c];
          r.x += s.x; r.y += s.y; r.z += s.z; r.w += s.w;
        }
        *(float4*)&sp[(size_t)t * RD + c] = r;
      }
    }
    return;
  }

  if (skip_rd) {
    const float* sp = skip_io + tilebase;
#pragma unroll
    for (int ct = 0; ct < 4; ++ct) {
      const int c = c0w + ct * 16 + q * 4;
#pragma unroll
      for (int tt = 0; tt < 4; ++tt) {
        const int t = t0w + tt * 16 + n;
        const float4 s = *(const float4*)&sp[(size_t)t * RD + c];
        acc[ct][tt][0] += s.x; acc[ct][tt][1] += s.y;
        acc[ct][tt][2] += s.z; acc[ct][tt][3] += s.w;
      }
    }
  }

  // relu(skip + bsum) -> buf0 ; post1 ; relu -> buf1 ; post2 halves -> out
  store_act_bf16(buf[0], acc, bsum, c0w, t0w, n, q);
  __syncthreads();
  zero_acc(acc);
  mfma_gemm(p1, buf[0], rows, c0w, n, q, acc);
  store_act_bf16(buf[1], acc, p1b, c0w, t0w, n, q);
  __syncthreads();

  for (int half = 0; half < 2; ++half) {
    zero_acc(acc);
    mfma_gemm(p2 + (size_t)half * RD * RD, buf[1], rows, c0w, n, q, acc);
    const size_t ob = ((size_t)b * QD + half * RD) * TLEN + t0;
#pragma unroll
    for (int ct = 0; ct < 4; ++ct) {
      const int c = c0w + ct * 16 + q * 4;
      const float4 bb = *(const float4*)&p2b[half * RD + c];
#pragma unroll
      for (int tt = 0; tt < 4; ++tt) {
        const int t = t0w + tt * 16 + n;
        const f32x4 A = acc[ct][tt];
        out[ob + (size_t)(c + 0) * TLEN + t] = A[0] + bb.x;
        out[ob + (size_t)(c + 1) * TLEN + t] = A[1] + bb.y;
        out[ob + (size_t)(c + 2) * TLEN + t] = A[2] + bb.z;
        out[ob + (size_t)(c + 3) * TLEN + t] = A[3] + bb.w;
      }
    }
  }
}

// ---------------------------------------------------------------------------
// Causal conv: x [B,1,T] -> fp32 [B][T][C] + bf16 relu copy
// ---------------------------------------------------------------------------
__global__ __launch_bounds__(256) void causal_kernel(const float* __restrict__ x,
                                                     const float* __restrict__ w,
                                                     const float* __restrict__ bias,
                                                     float* __restrict__ y,
                                                     unsigned short* __restrict__ yr) {
  __shared__ float xw[152];
  __shared__ float wl[RD * 25];
  __shared__ float bl[RD];
  const int tid = threadIdx.x;
  const int b   = blockIdx.x >> 7;
  const int t0  = (blockIdx.x & 127) << 7;
  for (int i = tid; i < RD * 25; i += 256) wl[i] = w[i];
  if (tid < RD) bl[tid] = bias[tid];
  for (int i = tid; i < 152; i += 256) {
    const int tg = t0 - 12 + i;
    xw[i] = ((unsigned)tg < (unsigned)TLEN) ? x[(size_t)b * TLEN + tg] : 0.f;
  }
  __syncthreads();
  const int c = tid & 127, tp = tid >> 7;
  float* yb = y + ((size_t)b * TLEN + t0) * RD + c;
  unsigned short* yrb = yr + ((size_t)b * TLEN + t0) * RD + c;
  const float bc = bl[c];
  for (int i = 0; i < 64; ++i) {
    const int tl = i * 2 + tp;
    float s = bc;
#pragma unroll
    for (int k = 0; k < 25; ++k) s = fmaf(wl[c * 25 + k], xw[tl + k], s);
    yb[(size_t)tl * RD] = s;
    yrb[(size_t)tl * RD] = (unsigned short)f2bf_relu(s);
  }
}

// ---------------------------------------------------------------------------
// Weight prep
// ---------------------------------------------------------------------------
__global__ __launch_bounds__(256) void cvt_kernel(const float* __restrict__ in,
                                                  unsigned short* __restrict__ out,
                                                  int total) {
  const int i = blockIdx.x * 256 + threadIdx.x;
  if (i < total) out[i] = f2bf(in[i]);
}
__global__ __launch_bounds__(256) void cvt_conv_kernel(const float* __restrict__ in,
                                                       unsigned short* __restrict__ out,
                                                       int total) {
  const int idx = blockIdx.x * 256 + threadIdx.x;
  if (idx >= total) return;
  const int ci = idx & 127, co = (idx >> 7) & 127, lk = idx >> 14;
  const int k = lk % 3, l = lk / 3;
  out[idx] = f2bf(in[(((size_t)l * RD + co) * RD + ci) * 3 + k]);
}
__global__ void bsum_kernel(const float* __restrict__ sb, float* __restrict__ bsum) {
  const int c = threadIdx.x;
  float s = 0.f;
  for (int l = N0SKIP; l < NLAYER; ++l) s += sb[l * RD + c];
  bsum[c] = s;
}

// ---------------------------------------------------------------------------
extern "C" void kernel_launch(void* const* d_in, const int* in_sizes, int n_in,
                              void* d_out, int out_size, void* d_ws, size_t ws_size,
                              hipStream_t stream) {
  const float* x        = (const float*)d_in[0];
  const float* causal_w = (const float*)d_in[1];
  const float* causal_b = (const float*)d_in[2];
  const float* dcnn_w   = (const float*)d_in[3];
  const float* dcnn_b   = (const float*)d_in[4];
  const float* dense_w  = (const float*)d_in[5];
  const float* dense_b  = (const float*)d_in[6];
  const float* skip_w   = (const float*)d_in[7];
  const float* skip_b   = (const float*)d_in[8];
  const float* post1_w  = (const float*)d_in[9];
  const float* post1_b  = (const float*)d_in[10];
  const float* post2_w  = (const float*)d_in[11];
  const float* post2_b  = (const float*)d_in[12];
  float* out = (float*)d_out;

  const size_t XNE = (size_t)NB * TLEN * RD;   // 16.78M elems

  // carve workspace
  char* p = (char*)d_ws;
  float* xA  = (float*)p;            p += XNE * 4;
  float* xB  = (float*)p;            p += XNE * 4;
  float* bsm = (float*)p;            p += 512;
  unsigned short* wc  = (unsigned short*)p; p += (size_t)NLAYER * 3 * RD * RD * 2;
  unsigned short* wd  = (unsigned short*)p; p += (size_t)NLAYER * RD * RD * 2;
  unsigned short* wsk = (unsigned short*)p; p += (size_t)NLAYER * RD * RD * 2;
  unsigned short* p1  = (unsigned short*)p; p += RD * RD * 2;
  unsigned short* p2  = (unsigned short*)p; p += QD * RD * 2;
  unsigned short* xrA = (unsigned short*)p; p += XNE * 2;
  unsigned short* xrB = (unsigned short*)p; p += XNE * 2;
  const size_t base_used = (size_t)(p - (char*)d_ws);

  // mode select by available scratch (constant across calls)
  const size_t need_full = base_used + (size_t)NSKIP * XNE * 2;
  const size_t need_g9   = base_used + XNE * 4 + (size_t)9 * XNE * 2;
  const size_t need_fb   = base_used + XNE * 4;
  int G;
  if (ws_size >= need_full)      G = NSKIP;
  else if (ws_size >= need_g9)   G = 9;
  else                           G = 0;   // per-layer skip RMW fallback

  float* skp = nullptr;
  unsigned short* hb = nullptr;
  if (G == NSKIP) {
    hb = (unsigned short*)p;
  } else {
    skp = (float*)p; p += XNE * 4;
    if (G == 9) hb = (unsigned short*)p;
  }

  // weight conversion
  const int tconv = NLAYER * 3 * RD * RD;
  const int t2    = NLAYER * RD * RD;
  cvt_conv_kernel<<<(tconv + 255) / 256, 256, 0, stream>>>(dcnn_w, wc, tconv);
  cvt_kernel<<<(t2 + 255) / 256, 256, 0, stream>>>(dense_w, wd, t2);
  cvt_kernel<<<(t2 + 255) / 256, 256, 0, stream>>>(skip_w, wsk, t2);
  cvt_kernel<<<(RD * RD + 255) / 256, 256, 0, stream>>>(post1_w, p1, RD * RD);
  cvt_kernel<<<(QD * RD + 255) / 256, 256, 0, stream>>>(post2_w, p2, QD * RD);
  if (G > 0) bsum_kernel<<<1, RD, 0, stream>>>(skip_b, bsm);
  else       hipMemsetAsync(bsm, 0, 512, stream);
  if (G == 0) hipMemsetAsync(skp, 0, XNE * 4, stream);

  causal_kernel<<<NB * (TLEN / TT), 256, 0, stream>>>(x, causal_w, causal_b, xA, xrA);

  const int grid = NB * (TLEN / TT);
  const float* xs = xA;  float* xd = xB;
  const unsigned short* xrs = xrA;  unsigned short* xrd = xrB;

  for (int l = 0; l < NLAYER; ++l) {
    const int dil = 1 << (l % 9);
    unsigned short* hout = nullptr;
    float* skarg = nullptr;
    if (l >= N0SKIP) {
      if (G > 0) hout = hb + (size_t)((l - N0SKIP) % G) * XNE;
      else       skarg = skp;
    }
    layer_kernel<<<grid, 256, 0, stream>>>(
        xrs, xs, xd, xrd, hout, skarg,
        wc  + (size_t)l * 3 * RD * RD, dcnn_b  + (size_t)l * RD,
        wd  + (size_t)l * RD * RD,     dense_b + (size_t)l * RD,
        wsk + (size_t)l * RD * RD,     skip_b  + (size_t)l * RD,
        dil);
    { const float* t = xs; xs = xd; xd = (float*)t; }
    { const unsigned short* t = xrs; xrs = xrd; xrd = (unsigned short*)t; }

    if (G == 9 && l >= N0SKIP && ((l - N0SKIP) % 9) == 8) {
      const int g = (l - N0SKIP) / 9;
      const int l0 = N0SKIP + g * 9;
      const int final_g = (g == 3);
      gather_kernel<<<grid, 256, 0, stream>>>(
          hb, 9, wsk + (size_t)l0 * RD * RD,
          skp, (g > 0) ? 1 : 0, final_g ? 0 : 1, final_g,
          bsm, p1, post1_b, p2, post2_b, out);
    }
  }

  if (G == NSKIP) {
    gather_kernel<<<grid, 256, 0, stream>>>(
        hb, NSKIP, wsk + (size_t)N0SKIP * RD * RD,
        nullptr, 0, 0, 1, bsm, p1, post1_b, p2, post2_b, out);
  } else if (G == 0) {
    gather_kernel<<<grid, 256, 0, stream>>>(
        nullptr, 0, nullptr, skp, 1, 0, 1, bsm, p1, post1_b, p2, post2_b, out);
  }
}

// Round 5
// 6029.226 us; speedup vs baseline: 1.2537x; 1.2537x over previous
//
#include <hip/hip_runtime.h>

#define RD     128
#define TT     128
#define TLEN   16384
#define NB     8
#define NLAYER 63
#define N0SKIP 27
#define NSKIP  36
#define QD     256
#define PADR   136   // LDS row stride in bf16 elems
#define CROWS  256   // staging window rows (69.6 KB -> 2 blocks/CU)

typedef short bf16x8 __attribute__((ext_vector_type(8)));
typedef float f32x4  __attribute__((ext_vector_type(4)));

__device__ __forceinline__ unsigned short f2bf(float f) {
  unsigned u = __float_as_uint(f);
  u += 0x7fffu + ((u >> 16) & 1u);
  return (unsigned short)(u >> 16);
}
__device__ __forceinline__ unsigned short f2bf_relu(float f) {
  f = f > 0.f ? f : 0.f;
  unsigned u = __float_as_uint(f);
  u += 0x7fffu + ((u >> 16) & 1u);
  return (unsigned short)(u >> 16);
}

__device__ __forceinline__ void zero_acc(f32x4 (&acc)[4][4]) {
#pragma unroll
  for (int i = 0; i < 4; ++i)
#pragma unroll
    for (int j = 0; j < 4; ++j) acc[i][j] = (f32x4){0.f, 0.f, 0.f, 0.f};
}

// ---------------------------------------------------------------------------
// 128-K GEMM on a 64c x 64t wave tile.
// ACT_A=true : D[m=t][n=c] (acc[ct][tt]: t = t0w+tt*16+q*4+r, c = c0w+ct*16+n)
// ACT_A=false: D[m=c][n=t] (acc[ct][tt]: c = c0w+ct*16+q*4+r, t = t0w+tt*16+n)
// w : bf16 global [c_out][c_in] (natural layout); sx: LDS bf16 [row][i]
// ---------------------------------------------------------------------------
template <bool ACT_A>
__device__ __forceinline__ void gemm128(const unsigned short* __restrict__ w,
                                        const short* sx, const int rows[4],
                                        int c0w, int n, int q, f32x4 (&acc)[4][4]) {
#pragma unroll
  for (int ks = 0; ks < 4; ++ks) {
    const int i0 = ks * 32 + q * 8;
    bf16x8 wf[4], af[4];
#pragma unroll
    for (int ct = 0; ct < 4; ++ct)
      wf[ct] = *(const bf16x8*)&w[(size_t)(c0w + ct * 16 + n) * RD + i0];
#pragma unroll
    for (int tt = 0; tt < 4; ++tt)
      af[tt] = *(const bf16x8*)&sx[rows[tt] * PADR + i0];
#pragma unroll
    for (int ct = 0; ct < 4; ++ct)
#pragma unroll
      for (int tt = 0; tt < 4; ++tt)
        acc[ct][tt] = ACT_A
          ? __builtin_amdgcn_mfma_f32_16x16x32_bf16(af[tt], wf[ct], acc[ct][tt], 0, 0, 0)
          : __builtin_amdgcn_mfma_f32_16x16x32_bf16(wf[ct], af[tt], acc[ct][tt], 0, 0, 0);
  }
}

// stage rows of xr (bf16 relu'd global [t][c]) into LDS [slot][i]
__device__ __forceinline__ void stage_xr(short* sx, const unsigned short* __restrict__ xg,
                                         int tstart, int nrows, int slot0, int tid) {
  const int tot = nrows << 4;
  for (int idx = tid; idx < tot; idx += 256) {
    const int r = idx >> 4, ck = (idx & 15) << 3;
    const int tg = tstart + r;
    uint4 v = {0u, 0u, 0u, 0u};
    if ((unsigned)tg < (unsigned)TLEN) v = *(const uint4*)&xg[(size_t)tg * RD + ck];
    *(uint4*)&sx[(slot0 + r) * PADR + ck] = v;
  }
}

// stage 128-row bf16 tile into LDS
__device__ __forceinline__ void stage_tile(short* dst, const unsigned short* __restrict__ src,
                                           int tid) {
  for (int idx = tid; idx < 128 * 16; idx += 256) {
    const int r = idx >> 4, ck = (idx & 15) << 3;
    *(uint4*)&dst[r * PADR + ck] = *(const uint4*)&src[(size_t)r * RD + ck];
  }
}

// relu(acc + bias) -> LDS bf16 [t][c]   (ACT_A orientation)
__device__ __forceinline__ void store_act(short* sx, const f32x4 (&acc)[4][4],
                                          const float* __restrict__ bias,
                                          int c0w, int t0w, int n, int q) {
#pragma unroll
  for (int ct = 0; ct < 4; ++ct) {
    const int c = c0w + ct * 16 + n;
    const float bb = bias[c];
#pragma unroll
    for (int tt = 0; tt < 4; ++tt) {
      const int tb = t0w + tt * 16 + q * 4;
#pragma unroll
      for (int r = 0; r < 4; ++r)
        sx[(tb + r) * PADR + c] = (short)f2bf_relu(acc[ct][tt][r] + bb);
    }
  }
}

// ---------------------------------------------------------------------------
// Fused WaveNet layer. x fp32 master [B][T][C]; xr = relu(x) bf16 staging copy.
// ---------------------------------------------------------------------------
__global__ __launch_bounds__(256, 2) void layer_kernel(
    const unsigned short* __restrict__ xr_in, const float* __restrict__ x_in,
    float* __restrict__ x_out, unsigned short* __restrict__ xr_out,
    unsigned short* __restrict__ h_out,   // bf16 h (deferred skip) or null
    float* __restrict__ skip,             // fp32 skip RMW fallback or null
    const unsigned short* __restrict__ wconv, const float* __restrict__ bconv,
    const unsigned short* __restrict__ wdense, const float* __restrict__ bdense,
    const unsigned short* __restrict__ wskip, const float* __restrict__ bskip,
    int dil) {
  __shared__ short sx[CROWS * PADR];   // 69,632 B

  const int tid = threadIdx.x;
  const int b   = blockIdx.x >> 7;
  const int t0  = (blockIdx.x & 127) << 7;
  const int lane = tid & 63;
  const int n = lane & 15, q = lane >> 4;
  const int wv = tid >> 6;
  const int c0w = (wv & 1) * 64, t0w = (wv >> 1) * 64;
  const unsigned short* xrb = xr_in + (size_t)b * TLEN * RD;

  f32x4 acc[4][4];
  zero_acc(acc);
  int rows[4];

  if (dil <= 64) {
    // window [t0-d, t0+128+d) <= 256 rows; tap k reads slot t_local + k*d
    stage_xr(sx, xrb, t0 - dil, 128 + 2 * dil, 0, tid);
    __syncthreads();
#pragma unroll
    for (int k = 0; k < 3; ++k) {
#pragma unroll
      for (int tt = 0; tt < 4; ++tt) rows[tt] = t0w + tt * 16 + n + k * dil;
      gemm128<true>(wconv + (size_t)k * RD * RD, sx, rows, c0w, n, q, acc);
    }
  } else {
    // d in {128,256}: disjoint tap tiles, ping-pong halves with overlap
    stage_xr(sx, xrb, t0 - dil, 128, 0, tid);
    __syncthreads();
    stage_xr(sx, xrb, t0, 128, 128, tid);        // tap1 -> slots 128..255
#pragma unroll
    for (int tt = 0; tt < 4; ++tt) rows[tt] = t0w + tt * 16 + n;
    gemm128<true>(wconv, sx, rows, c0w, n, q, acc);            // tap0
    __syncthreads();
    stage_xr(sx, xrb, t0 + dil, 128, 0, tid);    // tap2 -> slots 0..127
#pragma unroll
    for (int tt = 0; tt < 4; ++tt) rows[tt] = 128 + t0w + tt * 16 + n;
    gemm128<true>(wconv + (size_t)RD * RD, sx, rows, c0w, n, q, acc);  // tap1
    __syncthreads();
#pragma unroll
    for (int tt = 0; tt < 4; ++tt) rows[tt] = t0w + tt * 16 + n;
    gemm128<true>(wconv + (size_t)2 * RD * RD, sx, rows, c0w, n, q, acc); // tap2
  }
  __syncthreads();

  // h = relu(conv + bconv) -> LDS rows [0,128)
  store_act(sx, acc, bconv, c0w, t0w, n, q);
  __syncthreads();

  // deferred skip: stream h tile to global (coalesced from LDS)
  if (h_out) {
    unsigned short* hb = h_out + ((size_t)b * TLEN + t0) * RD;
    for (int idx = tid; idx < 128 * 16; idx += 256) {
      const int r = idx >> 4, ck = (idx & 15) << 3;
      *(uint4*)&hb[(size_t)r * RD + ck] = *(const uint4*)&sx[r * PADR + ck];
    }
  }

  // dense GEMM + fp32 residual + bf16 relu chain write
  zero_acc(acc);
#pragma unroll
  for (int tt = 0; tt < 4; ++tt) rows[tt] = t0w + tt * 16 + n;
  gemm128<true>(wdense, sx, rows, c0w, n, q, acc);
  {
    const size_t tb_g = ((size_t)b * TLEN + t0) * RD;
    const float* xi = x_in + tb_g;
    float* xo = x_out + tb_g;
    unsigned short* xro = xr_out + tb_g;
#pragma unroll
    for (int ct = 0; ct < 4; ++ct) {
      const int c = c0w + ct * 16 + n;
      const float bd = bdense[c];
#pragma unroll
      for (int tt = 0; tt < 4; ++tt) {
        const int tb = t0w + tt * 16 + q * 4;
#pragma unroll
        for (int r = 0; r < 4; ++r) {
          const int t = tb + r;
          const float v = xi[(size_t)t * RD + c] + acc[ct][tt][r] + bd;
          xo[(size_t)t * RD + c] = v;
          xro[(size_t)t * RD + c] = f2bf_relu(v);
        }
      }
    }
  }

  // fallback: per-layer fp32 skip RMW
  if (skip) {
    zero_acc(acc);
    gemm128<true>(wskip, sx, rows, c0w, n, q, acc);
    float* sp = skip + ((size_t)b * TLEN + t0) * RD;
#pragma unroll
    for (int ct = 0; ct < 4; ++ct) {
      const int c = c0w + ct * 16 + n;
      const float bs = bskip[c];
#pragma unroll
      for (int tt = 0; tt < 4; ++tt) {
        const int tb = t0w + tt * 16 + q * 4;
#pragma unroll
        for (int r = 0; r < 4; ++r) {
          const int t = tb + r;
          sp[(size_t)t * RD + c] += acc[ct][tt][r] + bs;
        }
      }
    }
  }
}

// ---------------------------------------------------------------------------
// Gather: skip-sum over nl h-buffers (double-buffered) + optional fused post.
// ---------------------------------------------------------------------------
__global__ __launch_bounds__(256, 2) void gather_kernel(
    const unsigned short* __restrict__ h, int nl,
    const unsigned short* __restrict__ wsk_g,
    float* __restrict__ skip_io, int skip_rd, int do_final,
    const float* __restrict__ bsum,
    const unsigned short* __restrict__ p1, const float* __restrict__ p1b,
    const unsigned short* __restrict__ p2, const float* __restrict__ p2b,
    float* __restrict__ out) {
  __shared__ short buf[2][128 * PADR];   // 69,632 B

  const int tid = threadIdx.x;
  const int b   = blockIdx.x >> 7;
  const int t0  = (blockIdx.x & 127) << 7;
  const int lane = tid & 63;
  const int n = lane & 15, q = lane >> 4;
  const int wv = tid >> 6;
  const int c0w = (wv & 1) * 64, t0w = (wv >> 1) * 64;
  const size_t tilebase = ((size_t)b * TLEN + t0) * RD;
  const size_t XNE = (size_t)NB * TLEN * RD;

  f32x4 acc[4][4];
  zero_acc(acc);
  int rows[4];
#pragma unroll
  for (int tt = 0; tt < 4; ++tt) rows[tt] = t0w + tt * 16 + n;

  if (nl > 0) {
    stage_tile(buf[0], h + tilebase, tid);
    __syncthreads();
    for (int li = 0; li < nl; ++li) {
      const int cur = li & 1;
      if (li + 1 < nl)
        stage_tile(buf[cur ^ 1], h + (size_t)(li + 1) * XNE + tilebase, tid);
      gemm128<true>(wsk_g + (size_t)li * RD * RD, buf[cur], rows, c0w, n, q, acc);
      __syncthreads();
    }
  }

  if (!do_final) {   // write or accumulate fp32 skip (D[t][c], coalesced dwords)
    float* sp = skip_io + tilebase;
#pragma unroll
    for (int ct = 0; ct < 4; ++ct) {
      const int c = c0w + ct * 16 + n;
#pragma unroll
      for (int tt = 0; tt < 4; ++tt) {
        const int tb = t0w + tt * 16 + q * 4;
#pragma unroll
        for (int r = 0; r < 4; ++r) {
          float v = acc[ct][tt][r];
          if (skip_rd) v += sp[(size_t)(tb + r) * RD + c];
          sp[(size_t)(tb + r) * RD + c] = v;
        }
      }
    }
    return;
  }

  if (skip_rd) {
    const float* sp = skip_io + tilebase;
#pragma unroll
    for (int ct = 0; ct < 4; ++ct) {
      const int c = c0w + ct * 16 + n;
#pragma unroll
      for (int tt = 0; tt < 4; ++tt) {
        const int tb = t0w + tt * 16 + q * 4;
#pragma unroll
        for (int r = 0; r < 4; ++r)
          acc[ct][tt][r] += sp[(size_t)(tb + r) * RD + c];
      }
    }
  }

  // relu(skip + bsum) -> buf0 ; post1 ; relu -> buf1
  store_act(buf[0], acc, bsum, c0w, t0w, n, q);
  __syncthreads();
  zero_acc(acc);
  gemm128<true>(p1, buf[0], rows, c0w, n, q, acc);
  store_act(buf[1], acc, p1b, c0w, t0w, n, q);
  __syncthreads();

  // post2 halves, reversed orientation -> D[c][t], coalesced [C][T] stores
  for (int half = 0; half < 2; ++half) {
    zero_acc(acc);
    gemm128<false>(p2 + (size_t)half * RD * RD, buf[1], rows, c0w, n, q, acc);
    const size_t obase = ((size_t)b * QD + half * RD) * TLEN + t0;
#pragma unroll
    for (int ct = 0; ct < 4; ++ct) {
      const int cb = c0w + ct * 16 + q * 4;
      const float4 bb = *(const float4*)&p2b[half * RD + cb];
      const float bv[4] = {bb.x, bb.y, bb.z, bb.w};
#pragma unroll
      for (int tt = 0; tt < 4; ++tt) {
        const int t = t0w + tt * 16 + n;
#pragma unroll
        for (int r = 0; r < 4; ++r)
          out[obase + (size_t)(cb + r) * TLEN + t] = acc[ct][tt][r] + bv[r];
      }
    }
  }
}

// ---------------------------------------------------------------------------
// Causal conv: x [B,1,T] -> fp32 [B][T][C] + bf16 relu copy
// ---------------------------------------------------------------------------
__global__ __launch_bounds__(256) void causal_kernel(const float* __restrict__ x,
                                                     const float* __restrict__ w,
                                                     const float* __restrict__ bias,
                                                     float* __restrict__ y,
                                                     unsigned short* __restrict__ yr) {
  __shared__ float xw[152];
  __shared__ float wl[RD * 25];
  __shared__ float bl[RD];
  const int tid = threadIdx.x;
  const int b   = blockIdx.x >> 7;
  const int t0  = (blockIdx.x & 127) << 7;
  for (int i = tid; i < RD * 25; i += 256) wl[i] = w[i];
  if (tid < RD) bl[tid] = bias[tid];
  for (int i = tid; i < 152; i += 256) {
    const int tg = t0 - 12 + i;
    xw[i] = ((unsigned)tg < (unsigned)TLEN) ? x[(size_t)b * TLEN + tg] : 0.f;
  }
  __syncthreads();
  const int c = tid & 127, tp = tid >> 7;
  float* yb = y + ((size_t)b * TLEN + t0) * RD + c;
  unsigned short* yrb = yr + ((size_t)b * TLEN + t0) * RD + c;
  const float bc = bl[c];
  for (int i = 0; i < 64; ++i) {
    const int tl = i * 2 + tp;
    float s = bc;
#pragma unroll
    for (int k = 0; k < 25; ++k) s = fmaf(wl[c * 25 + k], xw[tl + k], s);
    yb[(size_t)tl * RD] = s;
    yrb[(size_t)tl * RD] = f2bf_relu(s);
  }
}

// ---------------------------------------------------------------------------
// Weight prep
// ---------------------------------------------------------------------------
__global__ __launch_bounds__(256) void cvt_kernel(const float* __restrict__ in,
                                                  unsigned short* __restrict__ out,
                                                  int total) {
  const int i = blockIdx.x * 256 + threadIdx.x;
  if (i < total) out[i] = f2bf(in[i]);
}
// dcnn: [L][co][ci][3] -> [L][3][co][ci]
__global__ __launch_bounds__(256) void cvt_conv_kernel(const float* __restrict__ in,
                                                       unsigned short* __restrict__ out,
                                                       int total) {
  const int idx = blockIdx.x * 256 + threadIdx.x;
  if (idx >= total) return;
  const int ci = idx & 127, co = (idx >> 7) & 127, lk = idx >> 14;
  const int k = lk % 3, l = lk / 3;
  out[idx] = f2bf(in[(((size_t)l * RD + co) * RD + ci) * 3 + k]);
}
__global__ void bsum_kernel(const float* __restrict__ sb, float* __restrict__ bsum) {
  const int c = threadIdx.x;
  float s = 0.f;
  for (int l = N0SKIP; l < NLAYER; ++l) s += sb[l * RD + c];
  bsum[c] = s;
}

// ---------------------------------------------------------------------------
extern "C" void kernel_launch(void* const* d_in, const int* in_sizes, int n_in,
                              void* d_out, int out_size, void* d_ws, size_t ws_size,
                              hipStream_t stream) {
  const float* x        = (const float*)d_in[0];
  const float* causal_w = (const float*)d_in[1];
  const float* causal_b = (const float*)d_in[2];
  const float* dcnn_w   = (const float*)d_in[3];
  const float* dcnn_b   = (const float*)d_in[4];
  const float* dense_w  = (const float*)d_in[5];
  const float* dense_b  = (const float*)d_in[6];
  const float* skip_w   = (const float*)d_in[7];
  const float* skip_b   = (const float*)d_in[8];
  const float* post1_w  = (const float*)d_in[9];
  const float* post1_b  = (const float*)d_in[10];
  const float* post2_w  = (const float*)d_in[11];
  const float* post2_b  = (const float*)d_in[12];
  float* out = (float*)d_out;

  const size_t XNE = (size_t)NB * TLEN * RD;   // 16.78M elems

  char* p = (char*)d_ws;
  float* bsm = (float*)p;                    p += 512;
  unsigned short* wc  = (unsigned short*)p;  p += (size_t)NLAYER * 3 * RD * RD * 2;
  unsigned short* wd  = (unsigned short*)p;  p += (size_t)NLAYER * RD * RD * 2;
  unsigned short* wsk = (unsigned short*)p;  p += (size_t)NLAYER * RD * RD * 2;
  unsigned short* p1  = (unsigned short*)p;  p += RD * RD * 2;
  unsigned short* p2  = (unsigned short*)p;  p += QD * RD * 2;
  float* xA           = (float*)p;           p += XNE * 4;
  float* xB           = (float*)p;           p += XNE * 4;
  unsigned short* xrA = (unsigned short*)p;  p += XNE * 2;
  unsigned short* xrB = (unsigned short*)p;  p += XNE * 2;
  const size_t base_used = (size_t)(p - (char*)d_ws);

  const size_t need_full = base_used + (size_t)NSKIP * XNE * 2;
  const size_t need_g9   = base_used + XNE * 4 + (size_t)9 * XNE * 2;
  int G;
  if (ws_size >= need_full)    G = NSKIP;
  else if (ws_size >= need_g9) G = 9;
  else                         G = 0;

  float* skp = nullptr;
  unsigned short* hb = nullptr;
  if (G == NSKIP) {
    hb = (unsigned short*)p;
  } else {
    skp = (float*)p; p += XNE * 4;
    if (G == 9) hb = (unsigned short*)p;
  }

  const int tconv = NLAYER * 3 * RD * RD;
  const int t2    = NLAYER * RD * RD;
  cvt_conv_kernel<<<(tconv + 255) / 256, 256, 0, stream>>>(dcnn_w, wc, tconv);
  cvt_kernel<<<(t2 + 255) / 256, 256, 0, stream>>>(dense_w, wd, t2);
  cvt_kernel<<<(t2 + 255) / 256, 256, 0, stream>>>(skip_w, wsk, t2);
  cvt_kernel<<<(RD * RD + 255) / 256, 256, 0, stream>>>(post1_w, p1, RD * RD);
  cvt_kernel<<<(QD * RD + 255) / 256, 256, 0, stream>>>(post2_w, p2, QD * RD);
  if (G > 0) bsum_kernel<<<1, RD, 0, stream>>>(skip_b, bsm);
  else       hipMemsetAsync(bsm, 0, 512, stream);
  if (G == 0) hipMemsetAsync(skp, 0, XNE * 4, stream);

  const int grid = NB * (TLEN / TT);
  causal_kernel<<<grid, 256, 0, stream>>>(x, causal_w, causal_b, xA, xrA);

  const float* xs = xA;  float* xd = xB;
  const unsigned short* xrs = xrA;  unsigned short* xrd = xrB;

  for (int l = 0; l < NLAYER; ++l) {
    const int dil = 1 << (l % 9);
    unsigned short* hout = nullptr;
    float* skarg = nullptr;
    if (l >= N0SKIP) {
      if (G > 0) hout = hb + (size_t)((l - N0SKIP) % G) * XNE;
      else       skarg = skp;
    }
    layer_kernel<<<grid, 256, 0, stream>>>(
        xrs, xs, xd, xrd, hout, skarg,
        wc  + (size_t)l * 3 * RD * RD, dcnn_b  + (size_t)l * RD,
        wd  + (size_t)l * RD * RD,     dense_b + (size_t)l * RD,
        wsk + (size_t)l * RD * RD,     skip_b  + (size_t)l * RD,
        dil);
    { const float* t = xs; xs = xd; xd = (float*)t; }
    { const unsigned short* t = xrs; xrs = xrd; xrd = (unsigned short*)t; }

    if (G == 9 && l >= N0SKIP && ((l - N0SKIP) % 9) == 8) {
      const int g  = (l - N0SKIP) / 9;
      const int l0 = N0SKIP + g * 9;
      const int fg = (g == 3);
      gather_kernel<<<grid, 256, 0, stream>>>(
          hb, 9, wsk + (size_t)l0 * RD * RD,
          skp, (g > 0) ? 1 : 0, fg,
          bsm, p1, post1_b, p2, post2_b, out);
    }
  }

  if (G == NSKIP) {
    gather_kernel<<<grid, 256, 0, stream>>>(
        hb, NSKIP, wsk + (size_t)N0SKIP * RD * RD,
        nullptr, 0, 1, bsm, p1, post1_b, p2, post2_b, out);
  } else if (G == 0) {
    gather_kernel<<<grid, 256, 0, stream>>>(
        nullptr, 0, nullptr, skp, 1, 1, bsm, p1, post1_b, p2, post2_b, out);
  }
}